// Round 7
// baseline (179.665 us; speedup 1.0000x reference)
//
#include <hip/hip_runtime.h>
#include <hip/hip_bf16.h>

typedef float f2 __attribute__((ext_vector_type(2)));

// fast sigmoid / tanh via native v_exp_f32 + v_rcp_f32 (~1e-6 rel err vs threshold 7.8e-4)
__device__ __forceinline__ float sigf(float x) {
  return __builtin_amdgcn_rcpf(1.0f + __expf(-x));
}
__device__ __forceinline__ float tanh_fast(float x) {
  return fmaf(-2.0f, __builtin_amdgcn_rcpf(1.0f + __expf(2.0f * x)), 1.0f);
}

template<int CTRL>
__device__ __forceinline__ float dppf(float v) {
  return __builtin_bit_cast(float,
      __builtin_amdgcn_mov_dpp(__builtin_bit_cast(int, v), CTRL, 0xf, 0xf, false));
}

// Fan own-lane scalar h out to d[r] = h of lane (j^r), within quad-aligned 8-lane groups.
// xor1/2/3 = quad_perm; xor7 = row_half_mirror; xor4/5/6 = quad_perm ∘ xor7.
__device__ __forceinline__ void fanout8(float h, float* d) {
  d[0] = h;
  d[1] = dppf<0xB1>(h);      // quad_perm [1,0,3,2] = xor1
  d[2] = dppf<0x4E>(h);      // quad_perm [2,3,0,1] = xor2
  d[3] = dppf<0x1B>(h);      // quad_perm [3,2,1,0] = xor3
  float t7 = dppf<0x141>(h); // row_half_mirror     = xor7
  d[7] = t7;
  d[4] = dppf<0x1B>(t7);     // xor3∘xor7 = xor4
  d[5] = dppf<0x4E>(t7);     // xor2∘xor7 = xor5
  d[6] = dppf<0xB1>(t7);     // xor1∘xor7 = xor6
}

// B=16384, T=64, H=8. 8 lanes per batch element (lane j = hidden unit j).
// Block = 256 threads = 32 elements; grid = 512 blocks = 2 blocks/CU (2 waves/SIMD).
__launch_bounds__(256, 2)
__global__ void lstm_fused(
    const int* __restrict__ x,
    const float* __restrict__ e1, const float* __restrict__ e2,
    const float* __restrict__ e3, const float* __restrict__ e4,
    const float* __restrict__ e5, const float* __restrict__ e6,
    const float* __restrict__ e7, const float* __restrict__ e8,
    const float* __restrict__ W_ih0, const float* __restrict__ W_hh0,
    const float* __restrict__ b_ih0, const float* __restrict__ b_hh0,
    const float* __restrict__ W_ih1, const float* __restrict__ W_hh1,
    const float* __restrict__ b_ih1, const float* __restrict__ b_hh1,
    const float* __restrict__ fc6_w, const float* __restrict__ fc6_b,
    const float* __restrict__ fc7_w, const float* __restrict__ fc7_b,
    const float* __restrict__ fc1_w, const float* __restrict__ fc1_b,
    const float* __restrict__ fc2_w, const float* __restrict__ fc2_b,
    const float* __restrict__ fc3_w, const float* __restrict__ fc3_b,
    float* __restrict__ out)
{
  // Fused embedding×W_ih0 tables: 100 rows × 32 gate-values, per-unit permuted:
  // sTf[row*32 + j*4 + q]  (q: 0=i,1=f,2=g,3=o for unit j) -> float4 per (row,j)
  __shared__ __align__(16) float sTf[3200];
  __shared__ float sW3s[65];   // sW3s[0]=0, sW3s[t+1]=fc3_w[t]  (deferred-FC weight)

  const int tid = threadIdx.x;

  // ---- build fused input tables in LDS (one-time) ----
  {
    constexpr int RO[8]  = {0,2,4,25,47,52,54,76};
    constexpr int ED[8]  = {1,1,3,3,1,1,3,3};
    constexpr int CO[8]  = {0,1,2,5,8,9,10,13};
    constexpr int VOC[8] = {2,2,21,22,5,2,22,24};
    const float* ep[8] = {e1,e2,e3,e4,e5,e6,e7,e8};
    #pragma unroll
    for (int f = 0; f < 8; ++f) {
      const float* E = ep[f];
      for (int idx = tid; idx < VOC[f]*32; idx += 256) {
        int v = idx >> 5, m = idx & 31;
        int jj = m >> 2, q = m & 3, g = q*8 + jj;
        float s = 0.0f;
        #pragma unroll
        for (int d = 0; d < ED[f]; ++d)
          s += E[v*ED[f]+d] * W_ih0[g*16 + CO[f] + d];
        if (f == 0) s += b_ih0[g] + b_hh0[g];  // fold both biases into feat-0 table
        sTf[(RO[f]+v)*32 + m] = s;
      }
    }
    if (tid < 64) sW3s[tid+1] = fc3_w[tid];
    if (tid == 64) sW3s[0] = 0.f;
  }
  __syncthreads();

  const int j = tid & 7;                         // hidden unit owned by this lane
  const int b = (blockIdx.x << 5) + (tid >> 3);  // batch element

  // ---- per-lane recurrent weights, PRE-PERMUTED for the xor exchange:
  //      slot r pairs with h[j^r]; packed as gate-pairs (i,f) and (g,o) ----
  f2 wIF0[8], wGO0[8], iIF1[8], iGO1[8], rIF1[8], rGO1[8];
  #pragma unroll
  for (int r = 0; r < 8; ++r) {
    const int k = j ^ r;
    wIF0[r] = (f2){W_hh0[(0*8+j)*8+k], W_hh0[(1*8+j)*8+k]};
    wGO0[r] = (f2){W_hh0[(2*8+j)*8+k], W_hh0[(3*8+j)*8+k]};
    iIF1[r] = (f2){W_ih1[(0*8+j)*8+k], W_ih1[(1*8+j)*8+k]};
    iGO1[r] = (f2){W_ih1[(2*8+j)*8+k], W_ih1[(3*8+j)*8+k]};
    rIF1[r] = (f2){W_hh1[(0*8+j)*8+k], W_hh1[(1*8+j)*8+k]};
    rGO1[r] = (f2){W_hh1[(2*8+j)*8+k], W_hh1[(3*8+j)*8+k]};
  }
  const f2 bIF1 = {b_ih1[j]    + b_hh1[j],    b_ih1[8+j]  + b_hh1[8+j]};
  const f2 bGO1 = {b_ih1[16+j] + b_hh1[16+j], b_ih1[24+j] + b_hh1[24+j]};

  // ---- collapsed FC heads (theta,h) packed, pre-permuted like the matvecs ----
  float f7[4], f2c[4];
  #pragma unroll
  for (int q = 0; q < 4; ++q) { f7[q] = fc7_w[q]; f2c[q] = fc2_w[q]; }
  f2 uvk[8];
  #pragma unroll
  for (int r = 0; r < 8; ++r) {
    const int k = j ^ r;
    float s1 = 0.f, s2 = 0.f;
    #pragma unroll
    for (int q = 0; q < 4; ++q) {
      s1 += f7[q]  * fc6_w[q*8+k];
      s2 += f2c[q] * fc1_w[q*8+k];
    }
    uvk[r] = (f2){s1, s2};
  }
  float cth = fc7_b[0], chh = fc2_b[0];
  #pragma unroll
  for (int q = 0; q < 4; ++q) { cth += f7[q]*fc6_b[q]; chh += f2c[q]*fc1_b[q]; }
  const f2 cc = {cth, chh};
  const float fc3b = fc3_b[0];

  // ---- state (all in registers; no LDS in the recurrent path) ----
  float h0x[8], h1x[8];
  #pragma unroll
  for (int k = 0; k < 8; ++k) { h0x[k] = 0.f; h1x[k] = 0.f; }
  float c0 = 0.f, c1 = 0.f, acc = 0.f;

  const int4* xp = (const int4*)(x + (size_t)b * 512);
  const float4* tf4 = (const float4*)sTf;

  // prologue: gather t=0 rows; prefetch ids for t=1
  int4 ia = xp[0], ib = xp[1];
  float4 G0 = tf4[(      ia.x)*8 + j];
  float4 G1 = tf4[(  2 + ia.y)*8 + j];
  float4 G2 = tf4[(  4 + ia.z)*8 + j];
  float4 G3 = tf4[( 25 + ia.w)*8 + j];
  float4 G4 = tf4[( 47 + ib.x)*8 + j];
  float4 G5 = tf4[( 52 + ib.y)*8 + j];
  float4 G6 = tf4[( 54 + ib.z)*8 + j];
  float4 G7 = tf4[( 76 + ib.w)*8 + j];
  int4 na = xp[2], nb = xp[3];

  #pragma unroll 1
  for (int t = 0; t < 64; ++t) {
    const float w3p = sW3s[t];   // FC weight for step t-1 (0 at t=0)

    // (1) l0 gate sums from the gathers prefetched last iteration
    f2 sIFa = ((f2){G0.x,G0.y} + (f2){G1.x,G1.y}) + ((f2){G2.x,G2.y} + (f2){G3.x,G3.y});
    f2 sIFb = ((f2){G4.x,G4.y} + (f2){G5.x,G5.y}) + ((f2){G6.x,G6.y} + (f2){G7.x,G7.y});
    f2 sGOa = ((f2){G0.z,G0.w} + (f2){G1.z,G1.w}) + ((f2){G2.z,G2.w} + (f2){G3.z,G3.w});
    f2 sGOb = ((f2){G4.z,G4.w} + (f2){G5.z,G5.w}) + ((f2){G6.z,G6.w} + (f2){G7.z,G7.w});

    // (2) issue gathers for t+1 (a full step of latency to return)
    G0 = tf4[(      na.x)*8 + j];
    G1 = tf4[(  2 + na.y)*8 + j];
    G2 = tf4[(  4 + na.z)*8 + j];
    G3 = tf4[( 25 + na.w)*8 + j];
    G4 = tf4[( 47 + nb.x)*8 + j];
    G5 = tf4[( 52 + nb.y)*8 + j];
    G6 = tf4[( 54 + nb.z)*8 + j];
    G7 = tf4[( 76 + nb.w)*8 + j];

    // (3) prefetch ids for t+2 (clamped; tail reloads are harmless)
    {
      const int tn = (2*t + 4 <= 126) ? (2*t + 4) : 126;
      na = xp[tn]; nb = xp[tn+1];
    }

    // (4) layer-1 recurrent matvec + deferred FC(t-1) — independent of layer 0
    f2 GIFa = bIF1, GIFb = (f2){0.f,0.f}, GGOa = bGO1, GGOb = (f2){0.f,0.f};
    f2 thfa = cc,  thfb = (f2){0.f,0.f};
    #pragma unroll
    for (int r = 0; r < 8; r += 2) {
      f2 hA = (f2)(h1x[r]), hB = (f2)(h1x[r+1]);
      GIFa = __builtin_elementwise_fma(rIF1[r],   hA, GIFa);
      GIFb = __builtin_elementwise_fma(rIF1[r+1], hB, GIFb);
      GGOa = __builtin_elementwise_fma(rGO1[r],   hA, GGOa);
      GGOb = __builtin_elementwise_fma(rGO1[r+1], hB, GGOb);
      thfa = __builtin_elementwise_fma(uvk[r],    hA, thfa);
      thfb = __builtin_elementwise_fma(uvk[r+1],  hB, thfb);
    }
    f2 thf = thfa + thfb;
    acc = fmaf(thf.x * thf.y, w3p, acc);

    // (5) layer-0 recurrence (uses h0x fanned out at end of last step)
    #pragma unroll
    for (int r = 0; r < 8; r += 2) {
      sIFa = __builtin_elementwise_fma(wIF0[r],   (f2)(h0x[r]),   sIFa);
      sIFb = __builtin_elementwise_fma(wIF0[r+1], (f2)(h0x[r+1]), sIFb);
      sGOa = __builtin_elementwise_fma(wGO0[r],   (f2)(h0x[r]),   sGOa);
      sGOb = __builtin_elementwise_fma(wGO0[r+1], (f2)(h0x[r+1]), sGOb);
    }
    f2 gIF = sIFa + sIFb, gGO = sGOa + sGOb;
    float si = sigf(gIF.x), sf = sigf(gIF.y), tg = tanh_fast(gGO.x), so = sigf(gGO.y);
    c0 = fmaf(sf, c0, si * tg);
    float h0 = so * tanh_fast(c0);

    // (6) exchange h0 across the 8-lane group via DPP (no LDS)
    fanout8(h0, h0x);

    // (7) layer-1 input matvec + activations
    #pragma unroll
    for (int r = 0; r < 8; r += 2) {
      GIFa = __builtin_elementwise_fma(iIF1[r],   (f2)(h0x[r]),   GIFa);
      GIFb = __builtin_elementwise_fma(iIF1[r+1], (f2)(h0x[r+1]), GIFb);
      GGOa = __builtin_elementwise_fma(iGO1[r],   (f2)(h0x[r]),   GGOa);
      GGOb = __builtin_elementwise_fma(iGO1[r+1], (f2)(h0x[r+1]), GGOb);
    }
    f2 GIF = GIFa + GIFb, GGO = GGOa + GGOb;
    float si1 = sigf(GIF.x), sf1 = sigf(GIF.y), tg1 = tanh_fast(GGO.x), so1 = sigf(GGO.y);
    c1 = fmaf(sf1, c1, si1 * tg1);
    float h1 = so1 * tanh_fast(c1);

    // (8) exchange h1 via DPP for next step's r-matvec / FC
    fanout8(h1, h1x);
  }

  // epilogue: FC for t=63
  {
    f2 thfa = cc, thfb = (f2){0.f,0.f};
    #pragma unroll
    for (int r = 0; r < 8; r += 2) {
      thfa = __builtin_elementwise_fma(uvk[r],   (f2)(h1x[r]),   thfa);
      thfb = __builtin_elementwise_fma(uvk[r+1], (f2)(h1x[r+1]), thfb);
    }
    f2 thf = thfa + thfb;
    acc = fmaf(thf.x * thf.y, sW3s[64], acc);
  }

  if (j == 0) out[b] = acc + fc3b;
}

extern "C" void kernel_launch(void* const* d_in, const int* in_sizes, int n_in,
                              void* d_out, int out_size, void* d_ws, size_t ws_size,
                              hipStream_t stream) {
  const int* x = (const int*)d_in[0];
  const float *E1=(const float*)d_in[1],  *E2=(const float*)d_in[2],
              *E3=(const float*)d_in[3],  *E4=(const float*)d_in[4],
              *E5=(const float*)d_in[5],  *E6=(const float*)d_in[6],
              *E7=(const float*)d_in[7],  *E8=(const float*)d_in[8];
  const float *Wih0=(const float*)d_in[9],  *Whh0=(const float*)d_in[10],
              *bih0=(const float*)d_in[11], *bhh0=(const float*)d_in[12],
              *Wih1=(const float*)d_in[13], *Whh1=(const float*)d_in[14],
              *bih1=(const float*)d_in[15], *bhh1=(const float*)d_in[16],
              *fc6w=(const float*)d_in[17], *fc6b=(const float*)d_in[18],
              *fc7w=(const float*)d_in[19], *fc7b=(const float*)d_in[20],
              *fc1w=(const float*)d_in[21], *fc1b=(const float*)d_in[22],
              *fc2w=(const float*)d_in[23], *fc2b=(const float*)d_in[24],
              *fc3w=(const float*)d_in[25], *fc3b=(const float*)d_in[26];

  lstm_fused<<<512, 256, 0, stream>>>(
      x, E1,E2,E3,E4,E5,E6,E7,E8,
      Wih0, Whh0, bih0, bhh0, Wih1, Whh1, bih1, bhh1,
      fc6w, fc6b, fc7w, fc7b, fc1w, fc1b, fc2w, fc2b, fc3w, fc3b,
      (float*)d_out);
}

// Round 8
// 177.924 us; speedup vs baseline: 1.0098x; 1.0098x over previous
//
#include <hip/hip_runtime.h>
#include <hip/hip_bf16.h>

typedef float f2 __attribute__((ext_vector_type(2)));

// fast sigmoid / tanh via native v_exp_f32 + v_rcp_f32 (~1e-6 rel err vs threshold 7.8e-4)
__device__ __forceinline__ float sigf(float x) {
  return __builtin_amdgcn_rcpf(1.0f + __expf(-x));
}
__device__ __forceinline__ float tanh_fast(float x) {
  return fmaf(-2.0f, __builtin_amdgcn_rcpf(1.0f + __expf(2.0f * x)), 1.0f);
}

// B=16384, T=64, H=8. 8 lanes per batch element (lane j = hidden unit j),
// ILP-2: each 8-lane group runs TWO independent sequences (A,B) interleaved —
// converts the structurally-capped TLP (2 waves/SIMD) into in-wave ILP so the
// compiler fills dependency-stall slots with the sibling stream's work.
// Block = 256 threads = 32 groups = 64 elements; grid = 256 blocks = 1 block/CU.
__launch_bounds__(256, 1)
__global__ void lstm_fused(
    const int* __restrict__ x,
    const float* __restrict__ e1, const float* __restrict__ e2,
    const float* __restrict__ e3, const float* __restrict__ e4,
    const float* __restrict__ e5, const float* __restrict__ e6,
    const float* __restrict__ e7, const float* __restrict__ e8,
    const float* __restrict__ W_ih0, const float* __restrict__ W_hh0,
    const float* __restrict__ b_ih0, const float* __restrict__ b_hh0,
    const float* __restrict__ W_ih1, const float* __restrict__ W_hh1,
    const float* __restrict__ b_ih1, const float* __restrict__ b_hh1,
    const float* __restrict__ fc6_w, const float* __restrict__ fc6_b,
    const float* __restrict__ fc7_w, const float* __restrict__ fc7_b,
    const float* __restrict__ fc1_w, const float* __restrict__ fc1_b,
    const float* __restrict__ fc2_w, const float* __restrict__ fc2_b,
    const float* __restrict__ fc3_w, const float* __restrict__ fc3_b,
    float* __restrict__ out)
{
  // Fused embedding×W_ih0 tables: 100 rows × 32 gate-values, per-unit permuted:
  // sTf[row*32 + j*4 + q]  (q: 0=i,1=f,2=g,3=o for unit j) -> float4 per (row,j)
  __shared__ __align__(16) float sTf[3200];
  __shared__ float sW3s[65];   // sW3s[0]=0, sW3s[t+1]=fc3_w[t]  (deferred-FC weight)
  __shared__ __align__(16) float sH0[512];   // [0:256)=stream A, [256:512)=stream B
  __shared__ __align__(16) float sH1[512];

  const int tid = threadIdx.x;

  // ---- build fused input tables in LDS (one-time) ----
  {
    constexpr int RO[8]  = {0,2,4,25,47,52,54,76};
    constexpr int ED[8]  = {1,1,3,3,1,1,3,3};
    constexpr int CO[8]  = {0,1,2,5,8,9,10,13};
    constexpr int VOC[8] = {2,2,21,22,5,2,22,24};
    const float* ep[8] = {e1,e2,e3,e4,e5,e6,e7,e8};
    #pragma unroll
    for (int f = 0; f < 8; ++f) {
      const float* E = ep[f];
      for (int idx = tid; idx < VOC[f]*32; idx += 256) {
        int v = idx >> 5, m = idx & 31;
        int jj = m >> 2, q = m & 3, g = q*8 + jj;
        float s = 0.0f;
        #pragma unroll
        for (int d = 0; d < ED[f]; ++d)
          s += E[v*ED[f]+d] * W_ih0[g*16 + CO[f] + d];
        if (f == 0) s += b_ih0[g] + b_hh0[g];  // fold both biases into feat-0 table
        sTf[(RO[f]+v)*32 + m] = s;
      }
    }
    if (tid < 64) sW3s[tid+1] = fc3_w[tid];
    if (tid == 64) sW3s[0] = 0.f;
  }
  __syncthreads();

  const int j = tid & 7;                              // hidden unit owned by this lane
  const int bA = (blockIdx.x << 6) + ((tid >> 3) << 1);  // first of the elem pair

  // zero-init h1 slots (read at top of t=0; in-wave ordering suffices)
  sH1[tid] = 0.f;  sH1[256 + tid] = 0.f;

  // ---- shared per-lane weights packed as float2 gate-pairs (i,f)/(g,o) ----
  f2 wIF0[8], wGO0[8], iIF1[8], iGO1[8], rIF1[8], rGO1[8];
  {
    const float4* P;
    float4 I0,I1,F0,F1,G0_,G1_,O0,O1;
    #define LOADROWS(M) \
      P = (const float4*)(M); \
      I0 = P[(0*8+j)*2]; I1 = P[(0*8+j)*2+1]; \
      F0 = P[(1*8+j)*2]; F1 = P[(1*8+j)*2+1]; \
      G0_ = P[(2*8+j)*2]; G1_ = P[(2*8+j)*2+1]; \
      O0 = P[(3*8+j)*2]; O1 = P[(3*8+j)*2+1];
    #define PACK(dIF, dGO) \
      dIF[0]=(f2){I0.x,F0.x}; dIF[1]=(f2){I0.y,F0.y}; dIF[2]=(f2){I0.z,F0.z}; dIF[3]=(f2){I0.w,F0.w}; \
      dIF[4]=(f2){I1.x,F1.x}; dIF[5]=(f2){I1.y,F1.y}; dIF[6]=(f2){I1.z,F1.z}; dIF[7]=(f2){I1.w,F1.w}; \
      dGO[0]=(f2){G0_.x,O0.x}; dGO[1]=(f2){G0_.y,O0.y}; dGO[2]=(f2){G0_.z,O0.z}; dGO[3]=(f2){G0_.w,O0.w}; \
      dGO[4]=(f2){G1_.x,O1.x}; dGO[5]=(f2){G1_.y,O1.y}; dGO[6]=(f2){G1_.z,O1.z}; dGO[7]=(f2){G1_.w,O1.w};
    LOADROWS(W_hh0); PACK(wIF0, wGO0);
    LOADROWS(W_ih1); PACK(iIF1, iGO1);
    LOADROWS(W_hh1); PACK(rIF1, rGO1);
    #undef LOADROWS
    #undef PACK
  }
  const f2 bIF1 = {b_ih1[j]    + b_hh1[j],    b_ih1[8+j]  + b_hh1[8+j]};
  const f2 bGO1 = {b_ih1[16+j] + b_hh1[16+j], b_ih1[24+j] + b_hh1[24+j]};

  // ---- collapsed FC heads (theta,h) packed ----
  f2 uvk[8];
  float f7[4], f2c[4];
  #pragma unroll
  for (int q = 0; q < 4; ++q) { f7[q] = fc7_w[q]; f2c[q] = fc2_w[q]; }
  #pragma unroll
  for (int k = 0; k < 8; ++k) {
    float s1 = 0.f, s2 = 0.f;
    #pragma unroll
    for (int q = 0; q < 4; ++q) {
      s1 += f7[q]  * fc6_w[q*8+k];
      s2 += f2c[q] * fc1_w[q*8+k];
    }
    uvk[k] = (f2){s1, s2};
  }
  float cth = fc7_b[0], chh = fc2_b[0];
  #pragma unroll
  for (int q = 0; q < 4; ++q) { cth += f7[q]*fc6_b[q]; chh += f2c[q]*fc1_b[q]; }
  const f2 cc = {cth, chh};
  const float fc3b = fc3_b[0];

  // ---- per-stream state ----
  float h0sA[8], h0sB[8];
  #pragma unroll
  for (int k = 0; k < 8; ++k) { h0sA[k] = 0.f; h0sB[k] = 0.f; }
  float c0A = 0.f, c1A = 0.f, accA = 0.f;
  float c0B = 0.f, c1B = 0.f, accB = 0.f;

  const int4* xpA = (const int4*)(x + (size_t)bA * 512);
  const int4* xpB = xpA + 128;   // next element, contiguous
  const float4* tf4 = (const float4*)sTf;
  const float4* phA0 = (const float4*)&sH0[tid & ~7];
  const float4* phB0 = (const float4*)&sH0[256 + (tid & ~7)];
  const float4* phA1 = (const float4*)&sH1[tid & ~7];
  const float4* phB1 = (const float4*)&sH1[256 + (tid & ~7)];

  // prologue: gather t=0 rows for both streams; prefetch ids for t=1
  int4 iaA = xpA[0], ibA = xpA[1], iaB = xpB[0], ibB = xpB[1];
  float4 GA0 = tf4[(      iaA.x)*8 + j], GB0 = tf4[(      iaB.x)*8 + j];
  float4 GA1 = tf4[(  2 + iaA.y)*8 + j], GB1 = tf4[(  2 + iaB.y)*8 + j];
  float4 GA2 = tf4[(  4 + iaA.z)*8 + j], GB2 = tf4[(  4 + iaB.z)*8 + j];
  float4 GA3 = tf4[( 25 + iaA.w)*8 + j], GB3 = tf4[( 25 + iaB.w)*8 + j];
  float4 GA4 = tf4[( 47 + ibA.x)*8 + j], GB4 = tf4[( 47 + ibB.x)*8 + j];
  float4 GA5 = tf4[( 52 + ibA.y)*8 + j], GB5 = tf4[( 52 + ibB.y)*8 + j];
  float4 GA6 = tf4[( 54 + ibA.z)*8 + j], GB6 = tf4[( 54 + ibB.z)*8 + j];
  float4 GA7 = tf4[( 76 + ibA.w)*8 + j], GB7 = tf4[( 76 + ibB.w)*8 + j];
  int4 naA = xpA[2], nbA = xpA[3], naB = xpB[2], nbB = xpB[3];

  #pragma unroll 1
  for (int t = 0; t < 64; ++t) {
    const float w3p = sW3s[t];   // FC weight for step t-1 (0 at t=0)

    // (1) read h1(t-1) for both streams (written at end of t-1; full-body cover)
    float4 hA1a = phA1[0], hA1b = phA1[1];
    float4 hB1a = phB1[0], hB1b = phB1[1];
    float h1sA[8] = {hA1a.x,hA1a.y,hA1a.z,hA1a.w,hA1b.x,hA1b.y,hA1b.z,hA1b.w};
    float h1sB[8] = {hB1a.x,hB1a.y,hB1a.z,hB1a.w,hB1b.x,hB1b.y,hB1b.z,hB1b.w};

    // (2) l0 gate sums from gathers prefetched last iteration
    f2 sIFAa = ((f2){GA0.x,GA0.y} + (f2){GA1.x,GA1.y}) + ((f2){GA2.x,GA2.y} + (f2){GA3.x,GA3.y});
    f2 sIFAb = ((f2){GA4.x,GA4.y} + (f2){GA5.x,GA5.y}) + ((f2){GA6.x,GA6.y} + (f2){GA7.x,GA7.y});
    f2 sGOAa = ((f2){GA0.z,GA0.w} + (f2){GA1.z,GA1.w}) + ((f2){GA2.z,GA2.w} + (f2){GA3.z,GA3.w});
    f2 sGOAb = ((f2){GA4.z,GA4.w} + (f2){GA5.z,GA5.w}) + ((f2){GA6.z,GA6.w} + (f2){GA7.z,GA7.w});
    f2 sIFBa = ((f2){GB0.x,GB0.y} + (f2){GB1.x,GB1.y}) + ((f2){GB2.x,GB2.y} + (f2){GB3.x,GB3.y});
    f2 sIFBb = ((f2){GB4.x,GB4.y} + (f2){GB5.x,GB5.y}) + ((f2){GB6.x,GB6.y} + (f2){GB7.x,GB7.y});
    f2 sGOBa = ((f2){GB0.z,GB0.w} + (f2){GB1.z,GB1.w}) + ((f2){GB2.z,GB2.w} + (f2){GB3.z,GB3.w});
    f2 sGOBb = ((f2){GB4.z,GB4.w} + (f2){GB5.z,GB5.w}) + ((f2){GB6.z,GB6.w} + (f2){GB7.z,GB7.w});

    // (3) issue gathers for t+1 (a full step of latency to return)
    GA0 = tf4[(      naA.x)*8 + j];  GB0 = tf4[(      naB.x)*8 + j];
    GA1 = tf4[(  2 + naA.y)*8 + j];  GB1 = tf4[(  2 + naB.y)*8 + j];
    GA2 = tf4[(  4 + naA.z)*8 + j];  GB2 = tf4[(  4 + naB.z)*8 + j];
    GA3 = tf4[( 25 + naA.w)*8 + j];  GB3 = tf4[( 25 + naB.w)*8 + j];
    GA4 = tf4[( 47 + nbA.x)*8 + j];  GB4 = tf4[( 47 + nbB.x)*8 + j];
    GA5 = tf4[( 52 + nbA.y)*8 + j];  GB5 = tf4[( 52 + nbB.y)*8 + j];
    GA6 = tf4[( 54 + nbA.z)*8 + j];  GB6 = tf4[( 54 + nbB.z)*8 + j];
    GA7 = tf4[( 76 + nbA.w)*8 + j];  GB7 = tf4[( 76 + nbB.w)*8 + j];

    // (4) prefetch ids for t+2 (clamped; tail reloads harmless)
    {
      const int tn = (2*t + 4 <= 126) ? (2*t + 4) : 126;
      naA = xpA[tn]; nbA = xpA[tn+1];
      naB = xpB[tn]; nbB = xpB[tn+1];
    }

    // (5) layer-1 recurrent matvec + deferred FC(t-1), both streams
    f2 GIFA = bIF1, GGOA = bGO1, thfA = cc;
    f2 GIFB = bIF1, GGOB = bGO1, thfB = cc;
    #pragma unroll
    for (int k = 0; k < 8; ++k) {
      f2 hA = (f2)(h1sA[k]), hB = (f2)(h1sB[k]);
      GIFA = __builtin_elementwise_fma(rIF1[k], hA, GIFA);
      GGOA = __builtin_elementwise_fma(rGO1[k], hA, GGOA);
      thfA = __builtin_elementwise_fma(uvk[k],  hA, thfA);
      GIFB = __builtin_elementwise_fma(rIF1[k], hB, GIFB);
      GGOB = __builtin_elementwise_fma(rGO1[k], hB, GGOB);
      thfB = __builtin_elementwise_fma(uvk[k],  hB, thfB);
    }
    accA = fmaf(thfA.x * thfA.y, w3p, accA);
    accB = fmaf(thfB.x * thfB.y, w3p, accB);

    // (6) layer-0 recurrence, activations, write h0 (A then B)
    #pragma unroll
    for (int k = 0; k < 8; k += 2) {
      sIFAa = __builtin_elementwise_fma(wIF0[k],   (f2)(h0sA[k]),   sIFAa);
      sIFAb = __builtin_elementwise_fma(wIF0[k+1], (f2)(h0sA[k+1]), sIFAb);
      sGOAa = __builtin_elementwise_fma(wGO0[k],   (f2)(h0sA[k]),   sGOAa);
      sGOAb = __builtin_elementwise_fma(wGO0[k+1], (f2)(h0sA[k+1]), sGOAb);
      sIFBa = __builtin_elementwise_fma(wIF0[k],   (f2)(h0sB[k]),   sIFBa);
      sIFBb = __builtin_elementwise_fma(wIF0[k+1], (f2)(h0sB[k+1]), sIFBb);
      sGOBa = __builtin_elementwise_fma(wGO0[k],   (f2)(h0sB[k]),   sGOBa);
      sGOBb = __builtin_elementwise_fma(wGO0[k+1], (f2)(h0sB[k+1]), sGOBb);
    }
    f2 gIFA = sIFAa + sIFAb, gGOA = sGOAa + sGOAb;
    f2 gIFB = sIFBa + sIFBb, gGOB = sGOBa + sGOBb;
    float siA = sigf(gIFA.x), sfA = sigf(gIFA.y), tgA = tanh_fast(gGOA.x), soA = sigf(gGOA.y);
    float siB = sigf(gIFB.x), sfB = sigf(gIFB.y), tgB = tanh_fast(gGOB.x), soB = sigf(gGOB.y);
    c0A = fmaf(sfA, c0A, siA * tgA);
    c0B = fmaf(sfB, c0B, siB * tgB);
    float h0A = soA * tanh_fast(c0A);
    float h0B = soB * tanh_fast(c0B);
    sH0[tid] = h0A;
    sH0[256 + tid] = h0B;

    // (7) read h0 back (exchange across the 8-lane group)
    {
      float4 lo = phA0[0], hi = phA0[1];
      h0sA[0]=lo.x; h0sA[1]=lo.y; h0sA[2]=lo.z; h0sA[3]=lo.w;
      h0sA[4]=hi.x; h0sA[5]=hi.y; h0sA[6]=hi.z; h0sA[7]=hi.w;
    }
    {
      float4 lo = phB0[0], hi = phB0[1];
      h0sB[0]=lo.x; h0sB[1]=lo.y; h0sB[2]=lo.z; h0sB[3]=lo.w;
      h0sB[4]=hi.x; h0sB[5]=hi.y; h0sB[6]=hi.z; h0sB[7]=hi.w;
    }

    // (8) layer-1 input matvec, activations, write h1 (read deferred to t+1)
    #pragma unroll
    for (int k = 0; k < 8; ++k) {
      f2 hA = (f2)(h0sA[k]), hB = (f2)(h0sB[k]);
      GIFA = __builtin_elementwise_fma(iIF1[k], hA, GIFA);
      GGOA = __builtin_elementwise_fma(iGO1[k], hA, GGOA);
      GIFB = __builtin_elementwise_fma(iIF1[k], hB, GIFB);
      GGOB = __builtin_elementwise_fma(iGO1[k], hB, GGOB);
    }
    float si1A = sigf(GIFA.x), sf1A = sigf(GIFA.y), tg1A = tanh_fast(GGOA.x), so1A = sigf(GGOA.y);
    float si1B = sigf(GIFB.x), sf1B = sigf(GIFB.y), tg1B = tanh_fast(GGOB.x), so1B = sigf(GGOB.y);
    c1A = fmaf(sf1A, c1A, si1A * tg1A);
    c1B = fmaf(sf1B, c1B, si1B * tg1B);
    float h1A = so1A * tanh_fast(c1A);
    float h1B = so1B * tanh_fast(c1B);
    sH1[tid] = h1A;
    sH1[256 + tid] = h1B;
  }

  // epilogue: FC for t=63, both streams
  {
    float4 hA1a = phA1[0], hA1b = phA1[1];
    float4 hB1a = phB1[0], hB1b = phB1[1];
    float h1sA[8] = {hA1a.x,hA1a.y,hA1a.z,hA1a.w,hA1b.x,hA1b.y,hA1b.z,hA1b.w};
    float h1sB[8] = {hB1a.x,hB1a.y,hB1a.z,hB1a.w,hB1b.x,hB1b.y,hB1b.z,hB1b.w};
    f2 thfA = cc, thfB = cc;
    #pragma unroll
    for (int k = 0; k < 8; ++k) {
      thfA = __builtin_elementwise_fma(uvk[k], (f2)(h1sA[k]), thfA);
      thfB = __builtin_elementwise_fma(uvk[k], (f2)(h1sB[k]), thfB);
    }
    accA = fmaf(thfA.x * thfA.y, sW3s[64], accA);
    accB = fmaf(thfB.x * thfB.y, sW3s[64], accB);
  }

  if (j == 0) {
    out[bA]     = accA + fc3b;
    out[bA + 1] = accB + fc3b;
  }
}

extern "C" void kernel_launch(void* const* d_in, const int* in_sizes, int n_in,
                              void* d_out, int out_size, void* d_ws, size_t ws_size,
                              hipStream_t stream) {
  const int* x = (const int*)d_in[0];
  const float *E1=(const float*)d_in[1],  *E2=(const float*)d_in[2],
              *E3=(const float*)d_in[3],  *E4=(const float*)d_in[4],
              *E5=(const float*)d_in[5],  *E6=(const float*)d_in[6],
              *E7=(const float*)d_in[7],  *E8=(const float*)d_in[8];
  const float *Wih0=(const float*)d_in[9],  *Whh0=(const float*)d_in[10],
              *bih0=(const float*)d_in[11], *bhh0=(const float*)d_in[12],
              *Wih1=(const float*)d_in[13], *Whh1=(const float*)d_in[14],
              *bih1=(const float*)d_in[15], *bhh1=(const float*)d_in[16],
              *fc6w=(const float*)d_in[17], *fc6b=(const float*)d_in[18],
              *fc7w=(const float*)d_in[19], *fc7b=(const float*)d_in[20],
              *fc1w=(const float*)d_in[21], *fc1b=(const float*)d_in[22],
              *fc2w=(const float*)d_in[23], *fc2b=(const float*)d_in[24],
              *fc3w=(const float*)d_in[25], *fc3b=(const float*)d_in[26];

  lstm_fused<<<256, 256, 0, stream>>>(
      x, E1,E2,E3,E4,E5,E6,E7,E8,
      Wih0, Whh0, bih0, bhh0, Wih1, Whh1, bih1, bhh1,
      fc6w, fc6b, fc7w, fc7b, fc1w, fc1b, fc2w, fc2b, fc3w, fc3b,
      (float*)d_out);
}